// Round 2
// baseline (88.975 us; speedup 1.0000x reference)
//
#include <hip/hip_runtime.h>

// LaplacianLossBatch: B=16, NV=2562, NF=5120
// Exact reference semantics:
//   A[i,j] = 1 iff pair (i,j) set by any face (6 ordered pairs/face, SET semantics)
//   deg[i] = popcount(row i of A)  (includes diagonal bit from degenerate faces,
//            because the diag overwrite happens after edge sets in the reference)
//   v_avg[i] = deg>0 ? v[i] - (sum_{j!=i, A[i,j]} v[j]) / deg : 0
//   out = sum(v_avg^2)

constexpr int NV = 2562;
constexpr int NF = 5120;
constexpr int BATCH = 16;
constexpr int W = (NV + 31) / 32; // 81 words per bitmask row

__global__ void lap_build_mask(const int* __restrict__ faces,
                               unsigned int* __restrict__ mask,
                               int b0, int nb) {
    int idx = blockIdx.x * blockDim.x + threadIdx.x;
    int total = nb * NF;
    if (idx >= total) return;
    int bl = idx / NF;          // batch index within chunk
    int f  = idx - bl * NF;
    const int* fp = faces + ((size_t)(b0 + bl) * NF + f) * 3;
    int i0 = fp[0], i1 = fp[1], i2 = fp[2];
    unsigned int* m = mask + (size_t)bl * NV * W;
    auto setbit = [&](int i, int j) {
        atomicOr(&m[(size_t)i * W + (j >> 5)], 1u << (j & 31));
    };
    setbit(i0, i1); setbit(i1, i0);
    setbit(i1, i2); setbit(i2, i1);
    setbit(i2, i0); setbit(i0, i2);
}

__global__ void lap_scan_rows(const float* __restrict__ vertices,
                              const unsigned int* __restrict__ mask,
                              float* __restrict__ out,
                              int b0, int nb) {
    int idx = blockIdx.x * blockDim.x + threadIdx.x;
    int total = nb * NV;
    float local = 0.0f;
    if (idx < total) {
        int bl = idx / NV;
        int i  = idx - bl * NV;
        const unsigned int* row = mask + ((size_t)bl * NV + (size_t)i) * W;
        const float* vb = vertices + (size_t)(b0 + bl) * NV * 3;
        int deg = 0;
        float sx = 0.f, sy = 0.f, sz = 0.f;
        #pragma unroll 4
        for (int w = 0; w < W; ++w) {
            unsigned int bits = row[w];
            deg += __popc(bits);
            while (bits) {
                int b = __ffs(bits) - 1;
                bits &= bits - 1;
                int j = w * 32 + b;
                if (j != i) {  // diagonal counts in deg, not in the neighbor sum
                    sx += vb[3 * j];
                    sy += vb[3 * j + 1];
                    sz += vb[3 * j + 2];
                }
            }
        }
        if (deg > 0) {
            float inv = 1.0f / (float)deg;
            float ax = vb[3 * i]     - sx * inv;
            float ay = vb[3 * i + 1] - sy * inv;
            float az = vb[3 * i + 2] - sz * inv;
            local = ax * ax + ay * ay + az * az;
        }
    }
    // block reduction (wave64)
    __shared__ float red[4];  // 256 threads / 64
    #pragma unroll
    for (int off = 32; off > 0; off >>= 1)
        local += __shfl_down(local, off);
    int lane = threadIdx.x & 63;
    int wid  = threadIdx.x >> 6;
    if (lane == 0) red[wid] = local;
    __syncthreads();
    if (threadIdx.x == 0) {
        float s = red[0] + red[1] + red[2] + red[3];
        atomicAdd(out, s);
    }
}

extern "C" void kernel_launch(void* const* d_in, const int* in_sizes, int n_in,
                              void* d_out, int out_size, void* d_ws, size_t ws_size,
                              hipStream_t stream) {
    const float* vertices = (const float*)d_in[0];
    const int*   faces    = (const int*)d_in[1];
    float*       out      = (float*)d_out;

    const size_t per_batch_bytes = (size_t)NV * W * sizeof(unsigned int); // ~830 KB
    int G = (int)(ws_size / per_batch_bytes);
    if (G > BATCH) G = BATCH;
    if (G < 1) G = 1;  // requires >= ~830 KB of workspace

    // d_out is poisoned before timing and never restored between replays.
    hipMemsetAsync(d_out, 0, sizeof(float), stream);

    unsigned int* mask = (unsigned int*)d_ws;
    for (int b0 = 0; b0 < BATCH; b0 += G) {
        int nb = (BATCH - b0 < G) ? (BATCH - b0) : G;
        hipMemsetAsync(mask, 0, per_batch_bytes * (size_t)nb, stream);

        int totalF = nb * NF;
        lap_build_mask<<<(totalF + 255) / 256, 256, 0, stream>>>(faces, mask, b0, nb);

        int totalR = nb * NV;
        lap_scan_rows<<<(totalR + 255) / 256, 256, 0, stream>>>(vertices, mask, out, b0, nb);
    }
}

// Round 3
// 68.816 us; speedup vs baseline: 1.2929x; 1.2929x over previous
//
#include <hip/hip_runtime.h>

// LaplacianLossBatch: B=16, NV=2562, NF=5120
// Exact reference semantics (verified: absmax 0.0 in R1):
//   A[i,j] = 1 iff pair (i,j) set by any face (6 ordered pairs/face, SET semantics)
//   deg[i] = popcount(row i of A)  (diagonal bit included — degenerate faces)
//   v_avg[i] = deg>0 ? v[i] - (sum_{j!=i, A[i,j]} v[j]) / deg : 0
//   out = sum(v_avg^2)
//
// R2: wave-per-row scan (was thread-per-row: 161 blocks, 6.5% occupancy,
// latency-bound at 58us). 64 lanes split the 81 mask words; shfl_xor reduce.

constexpr int NV = 2562;
constexpr int NF = 5120;
constexpr int BATCH = 16;
constexpr int W = (NV + 31) / 32; // 81 words per bitmask row

__global__ void lap_build_mask(const int* __restrict__ faces,
                               unsigned int* __restrict__ mask,
                               int b0, int nb) {
    int idx = blockIdx.x * blockDim.x + threadIdx.x;
    int total = nb * NF;
    if (idx >= total) return;
    int bl = idx / NF;
    int f  = idx - bl * NF;
    const int* fp = faces + ((size_t)(b0 + bl) * NF + f) * 3;
    int i0 = fp[0], i1 = fp[1], i2 = fp[2];
    unsigned int* m = mask + (size_t)bl * NV * W;
    auto setbit = [&](int i, int j) {
        atomicOr(&m[(size_t)i * W + (j >> 5)], 1u << (j & 31));
    };
    setbit(i0, i1); setbit(i1, i0);
    setbit(i1, i2); setbit(i2, i1);
    setbit(i2, i0); setbit(i0, i2);
}

// One wave (64 lanes) per row; grid-stride over rows; one atomic per block.
__global__ void lap_scan_rows_wave(const float* __restrict__ vertices,
                                   const unsigned int* __restrict__ mask,
                                   float* __restrict__ out,
                                   int b0, int nb) {
    const int lane   = threadIdx.x & 63;
    const int wid    = threadIdx.x >> 6;           // wave in block (0..3)
    const int nwaves = (gridDim.x * blockDim.x) >> 6;
    int gwave = (blockIdx.x * blockDim.x + threadIdx.x) >> 6;
    const int total = nb * NV;

    float acc = 0.0f;  // meaningful on lane 0 of each wave
    for (int r = gwave; r < total; r += nwaves) {
        int bl = r / NV;
        int i  = r - bl * NV;
        const unsigned int* row = mask + ((size_t)bl * NV + (size_t)i) * W;
        const float* vb = vertices + (size_t)(b0 + bl) * NV * 3;

        float deg = 0.0f;                 // exact: deg <= 2562 < 2^24
        float sx = 0.f, sy = 0.f, sz = 0.f;
        // lane l covers words l and l+64 (coalesced)
        for (int w = lane; w < W; w += 64) {
            unsigned int bits = row[w];
            deg += (float)__popc(bits);
            while (bits) {
                int b = __ffs(bits) - 1;
                bits &= bits - 1;
                int j = w * 32 + b;
                if (j != i) {
                    sx += vb[3 * j];
                    sy += vb[3 * j + 1];
                    sz += vb[3 * j + 2];
                }
            }
        }
        // wave reduction, 6 levels
        #pragma unroll
        for (int off = 32; off > 0; off >>= 1) {
            deg += __shfl_down(deg, off);
            sx  += __shfl_down(sx,  off);
            sy  += __shfl_down(sy,  off);
            sz  += __shfl_down(sz,  off);
        }
        if (lane == 0 && deg > 0.5f) {
            float inv = 1.0f / deg;
            float ax = vb[3 * i]     - sx * inv;
            float ay = vb[3 * i + 1] - sy * inv;
            float az = vb[3 * i + 2] - sz * inv;
            acc += ax * ax + ay * ay + az * az;
        }
    }

    __shared__ float red[4];
    if (lane == 0) red[wid] = acc;
    __syncthreads();
    if (threadIdx.x == 0)
        atomicAdd(out, red[0] + red[1] + red[2] + red[3]);
}

extern "C" void kernel_launch(void* const* d_in, const int* in_sizes, int n_in,
                              void* d_out, int out_size, void* d_ws, size_t ws_size,
                              hipStream_t stream) {
    const float* vertices = (const float*)d_in[0];
    const int*   faces    = (const int*)d_in[1];
    float*       out      = (float*)d_out;

    const size_t per_batch_bytes = (size_t)NV * W * sizeof(unsigned int); // ~830 KB
    int G = (int)(ws_size / per_batch_bytes);
    if (G > BATCH) G = BATCH;
    if (G < 1) G = 1;

    hipMemsetAsync(d_out, 0, sizeof(float), stream);

    unsigned int* mask = (unsigned int*)d_ws;
    for (int b0 = 0; b0 < BATCH; b0 += G) {
        int nb = (BATCH - b0 < G) ? (BATCH - b0) : G;
        hipMemsetAsync(mask, 0, per_batch_bytes * (size_t)nb, stream);

        int totalF = nb * NF;
        lap_build_mask<<<(totalF + 255) / 256, 256, 0, stream>>>(faces, mask, b0, nb);

        // wave-per-row, grid-stride: 1024 blocks x 4 waves = 4096 waves (16/CU)
        lap_scan_rows_wave<<<1024, 256, 0, stream>>>(vertices, mask, out, b0, nb);
    }
}

// Round 4
// 64.278 us; speedup vs baseline: 1.3842x; 1.0706x over previous
//
#include <hip/hip_runtime.h>

// LaplacianLossBatch: B=16, NV=2562, NF=5120
// Exact reference semantics (verified: absmax 0.0 in R1/R2):
//   A[i,j] = 1 iff pair (i,j) set by any face (6 ordered pairs/face, SET semantics)
//   deg[i] = popcount(row i of A)  (diagonal bit included — degenerate faces)
//   v_avg[i] = deg>0 ? v[i] - (sum_{j!=i, A[i,j]} v[j]) / deg : 0
//   out = sum(v_avg^2)
//
// R2: wave-per-row scan (58us -> off top-5).
// R3: replace hipMemsetAsync(13.3MB) with custom grid-stride uint4 clear —
//     rocclr fillBufferAligned ran at 8.9% occupancy / ~325 GB/s = 41us of
//     the 68.8us total. Also folds d_out zeroing into the clear kernel.

constexpr int NV = 2562;
constexpr int NF = 5120;
constexpr int BATCH = 16;
constexpr int W = (NV + 31) / 32; // 81 words per bitmask row

// Zero `nwords` u32s of mask; zero *out if non-null (first chunk only).
__global__ void lap_clear(unsigned int* __restrict__ mask, size_t nwords,
                          float* __restrict__ out) {
    size_t tid    = (size_t)blockIdx.x * blockDim.x + threadIdx.x;
    size_t stride = (size_t)gridDim.x * blockDim.x;
    size_t n4 = nwords >> 2;
    uint4* m4 = (uint4*)mask;
    uint4 z; z.x = z.y = z.z = z.w = 0u;
    for (size_t k = tid; k < n4; k += stride) m4[k] = z;
    for (size_t k = (n4 << 2) + tid; k < nwords; k += stride) mask[k] = 0u;
    if (tid == 0 && out != nullptr) *out = 0.0f;
}

__global__ void lap_build_mask(const int* __restrict__ faces,
                               unsigned int* __restrict__ mask,
                               int b0, int nb) {
    int idx = blockIdx.x * blockDim.x + threadIdx.x;
    int total = nb * NF;
    if (idx >= total) return;
    int bl = idx / NF;
    int f  = idx - bl * NF;
    const int* fp = faces + ((size_t)(b0 + bl) * NF + f) * 3;
    int i0 = fp[0], i1 = fp[1], i2 = fp[2];
    unsigned int* m = mask + (size_t)bl * NV * W;
    auto setbit = [&](int i, int j) {
        atomicOr(&m[(size_t)i * W + (j >> 5)], 1u << (j & 31));
    };
    setbit(i0, i1); setbit(i1, i0);
    setbit(i1, i2); setbit(i2, i1);
    setbit(i2, i0); setbit(i0, i2);
}

// One wave (64 lanes) per row; grid-stride over rows; one atomic per block.
__global__ void lap_scan_rows_wave(const float* __restrict__ vertices,
                                   const unsigned int* __restrict__ mask,
                                   float* __restrict__ out,
                                   int b0, int nb) {
    const int lane   = threadIdx.x & 63;
    const int wid    = threadIdx.x >> 6;
    const int nwaves = (gridDim.x * blockDim.x) >> 6;
    int gwave = (blockIdx.x * blockDim.x + threadIdx.x) >> 6;
    const int total = nb * NV;

    float acc = 0.0f;
    for (int r = gwave; r < total; r += nwaves) {
        int bl = r / NV;
        int i  = r - bl * NV;
        const unsigned int* row = mask + ((size_t)bl * NV + (size_t)i) * W;
        const float* vb = vertices + (size_t)(b0 + bl) * NV * 3;

        float deg = 0.0f;
        float sx = 0.f, sy = 0.f, sz = 0.f;
        for (int w = lane; w < W; w += 64) {
            unsigned int bits = row[w];
            deg += (float)__popc(bits);
            while (bits) {
                int b = __ffs(bits) - 1;
                bits &= bits - 1;
                int j = w * 32 + b;
                if (j != i) {
                    sx += vb[3 * j];
                    sy += vb[3 * j + 1];
                    sz += vb[3 * j + 2];
                }
            }
        }
        #pragma unroll
        for (int off = 32; off > 0; off >>= 1) {
            deg += __shfl_down(deg, off);
            sx  += __shfl_down(sx,  off);
            sy  += __shfl_down(sy,  off);
            sz  += __shfl_down(sz,  off);
        }
        if (lane == 0 && deg > 0.5f) {
            float inv = 1.0f / deg;
            float ax = vb[3 * i]     - sx * inv;
            float ay = vb[3 * i + 1] - sy * inv;
            float az = vb[3 * i + 2] - sz * inv;
            acc += ax * ax + ay * ay + az * az;
        }
    }

    __shared__ float red[4];
    if (lane == 0) red[wid] = acc;
    __syncthreads();
    if (threadIdx.x == 0)
        atomicAdd(out, red[0] + red[1] + red[2] + red[3]);
}

extern "C" void kernel_launch(void* const* d_in, const int* in_sizes, int n_in,
                              void* d_out, int out_size, void* d_ws, size_t ws_size,
                              hipStream_t stream) {
    const float* vertices = (const float*)d_in[0];
    const int*   faces    = (const int*)d_in[1];
    float*       out      = (float*)d_out;

    const size_t per_batch_words = (size_t)NV * W;
    const size_t per_batch_bytes = per_batch_words * sizeof(unsigned int);
    int G = (int)(ws_size / per_batch_bytes);
    if (G > BATCH) G = BATCH;
    if (G < 1) G = 1;

    unsigned int* mask = (unsigned int*)d_ws;
    for (int b0 = 0; b0 < BATCH; b0 += G) {
        int nb = (BATCH - b0 < G) ? (BATCH - b0) : G;

        size_t nwords = per_batch_words * (size_t)nb;
        lap_clear<<<2048, 256, 0, stream>>>(mask, nwords,
                                            (b0 == 0) ? out : nullptr);

        int totalF = nb * NF;
        lap_build_mask<<<(totalF + 255) / 256, 256, 0, stream>>>(faces, mask, b0, nb);

        lap_scan_rows_wave<<<1024, 256, 0, stream>>>(vertices, mask, out, b0, nb);
    }
}

// Round 5
// 30.035 us; speedup vs baseline: 2.9623x; 2.1401x over previous
//
#include <hip/hip_runtime.h>

// LaplacianLossBatch: B=16, NV=2562, NF=5120
// Exact reference semantics (verified: absmax 0.0 in R1-R4):
//   A[i,j] = 1 iff pair (i,j) set by any face (6 ordered pairs/face, SET semantics)
//   deg[i] = popcount(row i of A)  (diagonal bit included — degenerate faces)
//   v_avg[i] = deg>0 ? v[i] - (sum_{j!=i, A[i,j]} v[j]) / deg : 0
//   out = sum(v_avg^2)
//
// R2: wave-per-row scan of global mask (58us scan -> ~10us).
// R3: custom clear of the 13.3MB global mask — still ~37us on critical path.
// R5: KILL the global mask. Row-tiled LDS bitmask (64 rows x 81 words =
//     20.7KB) + batch vertices staged in LDS (30.7KB). One fused kernel,
//     656 blocks; plain-store partials to d_ws (poison-immune, no atomics,
//     no clears); tiny deterministic reduce kernel.

constexpr int NV = 2562;
constexpr int NF = 5120;
constexpr int BATCH = 16;
constexpr int W = (NV + 31) / 32;            // 81 words per bitmask row
constexpr int TILE = 64;                     // rows per block
constexpr int NT = (NV + TILE - 1) / TILE;   // 41 tiles (last tile: 2 rows)
constexpr int THREADS = 512;                 // 8 waves

__global__ __launch_bounds__(THREADS)
void lap_fused(const float* __restrict__ vertices,
               const int* __restrict__ faces,
               float* __restrict__ partial) {
    __shared__ unsigned int m[TILE * W];     // 20736 B
    __shared__ float vsh[NV * 3];            // 30744 B
    __shared__ float red[THREADS / 64];

    const int tile = blockIdx.x;
    const int b    = blockIdx.y;
    const int v0   = tile * TILE;
    const int tid  = threadIdx.x;

    // phase 0: clear LDS mask + stage this batch's vertices (coalesced)
    for (int k = tid; k < TILE * W; k += THREADS) m[k] = 0u;
    const float* vb = vertices + (size_t)b * NV * 3;
    for (int k = tid; k < NV * 3; k += THREADS) vsh[k] = vb[k];
    __syncthreads();

    // phase 1: scan all faces of the batch; set bits for in-tile source rows
    const int* fb = faces + (size_t)b * NF * 3;
    for (int f = tid; f < NF; f += THREADS) {
        int i0 = fb[3 * f], i1 = fb[3 * f + 1], i2 = fb[3 * f + 2];
        auto setb = [&](int s, int d) {
            unsigned r = (unsigned)(s - v0);
            if (r < (unsigned)TILE)
                atomicOr(&m[r * W + (d >> 5)], 1u << (d & 31));
        };
        setb(i0, i1); setb(i1, i0);
        setb(i1, i2); setb(i2, i1);
        setb(i2, i0); setb(i0, i2);
    }
    __syncthreads();

    // phase 2: wave-per-row scan, everything LDS-resident
    const int lane = tid & 63;
    const int wid  = tid >> 6;
    const int nwaves = THREADS / 64;
    float acc = 0.f;                         // lane 0 of each wave
    int rows = NV - v0; if (rows > TILE) rows = TILE;
    for (int r = wid; r < rows; r += nwaves) {
        int i = v0 + r;
        const unsigned int* row = &m[r * W];
        float deg = 0.f, sx = 0.f, sy = 0.f, sz = 0.f;
        for (int w = lane; w < W; w += 64) {
            unsigned bits = row[w];
            deg += (float)__popc(bits);
            while (bits) {
                int bno = __ffs(bits) - 1;
                bits &= bits - 1;
                int j = w * 32 + bno;
                if (j != i) {   // diagonal in deg, not in the neighbor sum
                    sx += vsh[3 * j];
                    sy += vsh[3 * j + 1];
                    sz += vsh[3 * j + 2];
                }
            }
        }
        #pragma unroll
        for (int off = 32; off; off >>= 1) {
            deg += __shfl_down(deg, off);
            sx  += __shfl_down(sx,  off);
            sy  += __shfl_down(sy,  off);
            sz  += __shfl_down(sz,  off);
        }
        if (lane == 0 && deg > 0.5f) {
            float inv = 1.f / deg;
            float ax = vsh[3 * i]     - sx * inv;
            float ay = vsh[3 * i + 1] - sy * inv;
            float az = vsh[3 * i + 2] - sz * inv;
            acc += ax * ax + ay * ay + az * az;
        }
    }
    if (lane == 0) red[wid] = acc;
    __syncthreads();
    if (tid == 0) {
        float s = 0.f;
        #pragma unroll
        for (int k = 0; k < THREADS / 64; ++k) s += red[k];
        partial[(size_t)b * gridDim.x + tile] = s;  // plain store: poison-immune
    }
}

__global__ void lap_reduce(const float* __restrict__ partial, int n,
                           float* __restrict__ out) {
    float local = 0.f;
    for (int k = threadIdx.x; k < n; k += blockDim.x) local += partial[k];
    #pragma unroll
    for (int off = 32; off; off >>= 1) local += __shfl_down(local, off);
    __shared__ float red[4];
    int lane = threadIdx.x & 63, wid = threadIdx.x >> 6;
    if (lane == 0) red[wid] = local;
    __syncthreads();
    if (threadIdx.x == 0) out[0] = red[0] + red[1] + red[2] + red[3];
}

extern "C" void kernel_launch(void* const* d_in, const int* in_sizes, int n_in,
                              void* d_out, int out_size, void* d_ws, size_t ws_size,
                              hipStream_t stream) {
    const float* vertices = (const float*)d_in[0];
    const int*   faces    = (const int*)d_in[1];
    float*       out      = (float*)d_out;
    float*       partial  = (float*)d_ws;    // NT*BATCH = 656 floats (2.6 KB)

    lap_fused<<<dim3(NT, BATCH), THREADS, 0, stream>>>(vertices, faces, partial);
    lap_reduce<<<1, 256, 0, stream>>>(partial, NT * BATCH, out);
}

// Round 6
// 18.913 us; speedup vs baseline: 4.7043x; 1.5881x over previous
//
#include <hip/hip_runtime.h>

// LaplacianLossBatch: B=16, NV=2562, NF=5120
// Exact reference semantics (verified: absmax 0.0 in R1-R5):
//   A[i,j] = 1 iff pair (i,j) set by any face (6 ordered pairs/face, SET semantics)
//   deg[i] = popcount(row i of A)  (diagonal bit included — degenerate faces)
//   v_avg[i] = deg>0 ? v[i] - (sum_{j!=i, A[i,j]} v[j]) / deg : 0
//   out = sum(v_avg^2)
//
// R5: fused LDS-tiled kernel (64 rows x 81 words mask + staged vertices),
//     plain-store partials, tiny reduce. 30.0us.
// R6: phase 2 restructured to 4 rows/wave x 16 lanes/row — shuffle-reduce
//     drops from 24/row to 4/row (192 -> 34 shuffles per wave). float2
//     vertex staging, float4 partial loads in reduce.

constexpr int NV = 2562;
constexpr int NF = 5120;
constexpr int BATCH = 16;
constexpr int W = (NV + 31) / 32;            // 81 words per bitmask row
constexpr int TILE = 64;                     // rows per block
constexpr int NT = (NV + TILE - 1) / TILE;   // 41 tiles (last tile: 2 rows)
constexpr int THREADS = 512;                 // 8 waves

__global__ __launch_bounds__(THREADS)
void lap_fused(const float* __restrict__ vertices,
               const int* __restrict__ faces,
               float* __restrict__ partial) {
    __shared__ unsigned int m[TILE * W];             // 20736 B
    __shared__ __align__(16) float vsh[NV * 3];      // 30744 B
    __shared__ float red[THREADS / 64];

    const int tile = blockIdx.x;
    const int b    = blockIdx.y;
    const int v0   = tile * TILE;
    const int tid  = threadIdx.x;

    // phase 0: clear LDS mask + stage this batch's vertices (float2: the
    // per-batch base (b*30744 bytes) is only 8B-aligned for odd b)
    for (int k = tid; k < TILE * W; k += THREADS) m[k] = 0u;
    const float2* vb2 = (const float2*)(vertices + (size_t)b * NV * 3);
    float2* vsh2 = (float2*)vsh;
    constexpr int NV3_2 = (NV * 3) / 2;              // 3843 float2, exact
    for (int k = tid; k < NV3_2; k += THREADS) vsh2[k] = vb2[k];
    __syncthreads();

    // phase 1: scan all faces of the batch; set bits for in-tile source rows
    const int* fb = faces + (size_t)b * NF * 3;
    for (int f = tid; f < NF; f += THREADS) {
        int i0 = fb[3 * f], i1 = fb[3 * f + 1], i2 = fb[3 * f + 2];
        auto setb = [&](int s, int d) {
            unsigned r = (unsigned)(s - v0);
            if (r < (unsigned)TILE)
                atomicOr(&m[r * W + (d >> 5)], 1u << (d & 31));
        };
        setb(i0, i1); setb(i1, i0);
        setb(i1, i2); setb(i2, i1);
        setb(i2, i0); setb(i0, i2);
    }
    __syncthreads();

    // phase 2: 4 rows per wave, 16 lanes per row; 2 passes cover 64 rows.
    const int lane = tid & 63;
    const int wid  = tid >> 6;
    const int g    = lane >> 4;      // row group within wave (0..3)
    const int s    = lane & 15;      // sublane within row group
    const int rows = min(TILE, NV - v0);
    float acc = 0.f;                 // nonzero only on s==0 lanes

    #pragma unroll
    for (int pass = 0; pass < TILE / 32; ++pass) {
        int r = pass * 32 + wid * 4 + g;
        float deg = 0.f, sx = 0.f, sy = 0.f, sz = 0.f;
        int i = v0 + r;
        if (r < rows) {
            const unsigned int* row = &m[r * W];
            for (int w = s; w < W; w += 16) {
                unsigned bits = row[w];
                deg += (float)__popc(bits);
                while (bits) {
                    int bno = __ffs(bits) - 1;
                    bits &= bits - 1;
                    int j = w * 32 + bno;
                    if (j != i) {    // diagonal in deg, not in neighbor sum
                        sx += vsh[3 * j];
                        sy += vsh[3 * j + 1];
                        sz += vsh[3 * j + 2];
                    }
                }
            }
        }
        // reduce within each 16-lane group (xor 1,2,4,8 stays in-group)
        #pragma unroll
        for (int off = 1; off <= 8; off <<= 1) {
            deg += __shfl_xor(deg, off);
            sx  += __shfl_xor(sx,  off);
            sy  += __shfl_xor(sy,  off);
            sz  += __shfl_xor(sz,  off);
        }
        if (s == 0 && r < rows && deg > 0.5f) {
            float inv = 1.f / deg;
            float ax = vsh[3 * i]     - sx * inv;
            float ay = vsh[3 * i + 1] - sy * inv;
            float az = vsh[3 * i + 2] - sz * inv;
            acc += ax * ax + ay * ay + az * az;
        }
    }
    // fold the 4 group-lanes (0,16,32,48); other lanes carry 0
    acc += __shfl_xor(acc, 16);
    acc += __shfl_xor(acc, 32);
    if (lane == 0) red[wid] = acc;
    __syncthreads();
    if (tid == 0) {
        float t = 0.f;
        #pragma unroll
        for (int k = 0; k < THREADS / 64; ++k) t += red[k];
        partial[(size_t)b * gridDim.x + tile] = t;   // plain store: poison-immune
    }
}

__global__ void lap_reduce(const float* __restrict__ partial, int n4,
                           float* __restrict__ out) {
    // n4 float4 elements (n4*4 floats, exact multiple by construction)
    const float4* p4 = (const float4*)partial;
    float local = 0.f;
    for (int k = threadIdx.x; k < n4; k += blockDim.x) {
        float4 v = p4[k];
        local += (v.x + v.y) + (v.z + v.w);
    }
    #pragma unroll
    for (int off = 32; off; off >>= 1) local += __shfl_down(local, off);
    __shared__ float red[4];
    int lane = threadIdx.x & 63, wid = threadIdx.x >> 6;
    if (lane == 0) red[wid] = local;
    __syncthreads();
    if (threadIdx.x == 0) out[0] = red[0] + red[1] + red[2] + red[3];
}

extern "C" void kernel_launch(void* const* d_in, const int* in_sizes, int n_in,
                              void* d_out, int out_size, void* d_ws, size_t ws_size,
                              hipStream_t stream) {
    const float* vertices = (const float*)d_in[0];
    const int*   faces    = (const int*)d_in[1];
    float*       out      = (float*)d_out;
    float*       partial  = (float*)d_ws;    // NT*BATCH = 656 floats (2.6 KB)

    lap_fused<<<dim3(NT, BATCH), THREADS, 0, stream>>>(vertices, faces, partial);
    static_assert((NT * BATCH) % 4 == 0, "reduce uses float4");
    lap_reduce<<<1, 256, 0, stream>>>(partial, (NT * BATCH) / 4, out);
}